// Round 5
// baseline (590.318 us; speedup 1.0000x reference)
//
#include <hip/hip_runtime.h>
#include <hip/hip_bf16.h>
#include <cstdint>

typedef float  f32x4 __attribute__((ext_vector_type(4)));
typedef short  s16x4 __attribute__((ext_vector_type(4)));
typedef short  s16x8 __attribute__((ext_vector_type(8)));
typedef __bf16 bf16x8 __attribute__((ext_vector_type(8)));
typedef unsigned int u32x2 __attribute__((ext_vector_type(2)));
typedef unsigned int u32x4 __attribute__((ext_vector_type(4)));

static __device__ __forceinline__ unsigned short f2bf(float f) {
  union { float f; unsigned u; } v; v.f = f;
  unsigned r = v.u + 0x7fffu + ((v.u >> 16) & 1u);   // RTNE
  return (unsigned short)(r >> 16);
}

// packed fp32 pair -> 2x bf16 in one VALU op (RTNE), lo -> bits[15:0]
static __device__ __forceinline__ unsigned pk2(float lo, float hi) {
  unsigned r;
  asm("v_cvt_pk_bf16_f32 %0, %1, %2" : "=v"(r) : "v"(lo), "v"(hi));
  return r;
}

static __device__ __forceinline__ f32x4 mfma16(bf16x8 a, bf16x8 b, f32x4 c) {
  return __builtin_amdgcn_mfma_f32_16x16x32_bf16(a, b, c, 0, 0, 0);
}

// ---------------------------------------------------------------------------
// k_mlp: fused per-ROI 2-layer MLP.
// Round-5: R3's minimal-issued-traffic geometry (M=128 x N=128, grid 256 =
// 64 r x 4 c: X fan-out 4, W1 read exactly once => ~536 MB issued, the
// minimum any config achieved) + PREFETCH DEPTH 2: two register staging
// sets, tile ks+2's global loads issued at step ks. Load->use distance
// ~2 K-steps (~1200 cyc) > HBM miss latency (~900 cyc), so the s_waitcnt
// before storeTile no longer stalls — fixing the reason R3's traffic win
// didn't show (1 block/CU had no co-resident block to hide the stall).
// K=2048 in 32 steps of BK=64. Epilogue identical to R3 (verified).
// ---------------------------------------------------------------------------
__global__ __launch_bounds__(512)
void k_mlp(const float* __restrict__ X, const float* __restrict__ W1,
           const float* __restrict__ b1, const float* __restrict__ W2,
           float* __restrict__ m1)
{
  __shared__ short lds_a[128 * 72];    // [m][k] bf16, k padded 64->72
  __shared__ short lds_b[128 * 72];    // [n][k] bf16
  __shared__ short lds_h[128 * 136];   // layer2 A: [m][kh] bf16, kh 128->136
  __shared__ short lds_w2[32 * 136];   // layer2 B: [o][kh] bf16 (o>=20 zero)
  __shared__ float biasS[128];

  const int bid = blockIdx.x;
  // XCD swizzle: the 4 c-slices of one r land on the same XCD (bid mod 8)
  const int r = (bid & 7) + ((bid >> 5) << 3);
  const int c = (bid >> 3) & 3;

  const float* xr = X + (long)r * (128 * 2048);
  const float* wr = W1 + (long)r * (2048 * 512) + c * 128;
  const float* bp = b1 + (long)r * 512 + c * 128;

  const int t = threadIdx.x;
  const int lane = t & 63;
  const int w = t >> 6;                // 0..7

  if (t < 128) biasS[t] = bp[t];

  // staging maps (BK=64)
  const int aRow = t >> 2;             // 0..127
  const int aCol = (t & 3) * 4;        // within-row float offset, +16j
  const int bn   = t & 127;            // 0..127
  const int bk0  = (t >> 7) * 8;       // k-chunk base: 0,8,16,24 (+32 for g=1)

  // two staging register sets for prefetch depth 2
  f32x4 aR[2][4];
  float bR[2][2][8];

  auto loadTile = [&](int ks, int s) {
    const float* xp = xr + (long)aRow * 2048 + ks * 64 + aCol;
#pragma unroll
    for (int j = 0; j < 4; j++)
      aR[s][j] = *(const f32x4*)(xp + 16 * j);
    const float* wp = wr + (long)(ks * 64 + bk0) * 512 + bn;
#pragma unroll
    for (int g = 0; g < 2; g++)
#pragma unroll
      for (int j = 0; j < 8; j++)
        bR[s][g][j] = wp[(long)(g * 32 + j) * 512];
  };

  auto storeTile = [&](int s) {
#pragma unroll
    for (int j = 0; j < 4; j++) {
      u32x2 v;
      v[0] = pk2(aR[s][j][0], aR[s][j][1]);
      v[1] = pk2(aR[s][j][2], aR[s][j][3]);
      *(u32x2*)&lds_a[aRow * 72 + aCol + 16 * j] = v;
    }
#pragma unroll
    for (int g = 0; g < 2; g++) {
      u32x4 v;
      v[0] = pk2(bR[s][g][0], bR[s][g][1]);
      v[1] = pk2(bR[s][g][2], bR[s][g][3]);
      v[2] = pk2(bR[s][g][4], bR[s][g][5]);
      v[3] = pk2(bR[s][g][6], bR[s][g][7]);
      *(u32x4*)&lds_b[bn * 72 + bk0 + g * 32] = v;
    }
  };

  // 8 waves as 2(m) x 4(n): each wave 64m x 32n; per step 4x2x2 MFMAs
  const int wm = w & 1, wn = w >> 1;
  const int mBase = wm * 64, nBase = wn * 32;
  const int lm = lane & 15, lg = lane >> 4;

  f32x4 acc[4][2];
#pragma unroll
  for (int i = 0; i < 4; i++)
#pragma unroll
    for (int j = 0; j < 2; j++) acc[i][j] = f32x4{0.f, 0.f, 0.f, 0.f};

  loadTile(0, 0);
  loadTile(1, 1);
  for (int ks = 0; ks < 32; ks++) {
    const int s = ks & 1;
    __syncthreads();
    storeTile(s);
    __syncthreads();
    if (ks + 2 < 32) loadTile(ks + 2, s);
    bf16x8 af[2][4], bfr[2][2];
#pragma unroll
    for (int g = 0; g < 2; g++) {
#pragma unroll
      for (int i = 0; i < 4; i++)
        af[g][i] = *(const bf16x8*)&lds_a[(mBase + i * 16 + lm) * 72 + g * 32 + lg * 8];
#pragma unroll
      for (int j = 0; j < 2; j++)
        bfr[g][j] = *(const bf16x8*)&lds_b[(nBase + j * 16 + lm) * 72 + g * 32 + lg * 8];
    }
#pragma unroll
    for (int mi = 0; mi < 4; mi++)
#pragma unroll
      for (int ni = 0; ni < 2; ni++) {
        acc[mi][ni] = mfma16(af[0][mi], bfr[0][ni], acc[mi][ni]);
        acc[mi][ni] = mfma16(af[1][mi], bfr[1][ni], acc[mi][ni]);
      }
  }

  // h = relu(acc + b1) -> lds_h (bf16, A-layout [m][kh], kh = HID-slice col)
#pragma unroll
  for (int mi = 0; mi < 4; mi++)
#pragma unroll
    for (int ni = 0; ni < 2; ni++) {
      const int col = nBase + ni * 16 + lm;      // 0..127
      const float bv = biasS[col];
#pragma unroll
      for (int i = 0; i < 4; i++) {
        const int row = mBase + mi * 16 + lg * 4 + i;
        float v = acc[mi][ni][i] + bv;
        v = v > 0.f ? v : 0.f;
        lds_h[row * 136 + col] = (short)f2bf(v);
      }
    }
  // stage W2 slice [kh 0..127][o 0..19] -> lds_w2[o][kh], zero-pad o>=20
  {
    const float* w2r = W2 + (long)r * (512 * 20) + (long)(c * 128) * 20;
#pragma unroll
    for (int i = 0; i < 8; i++) {
      const int idx = t * 8 + i;            // 0..4095
      const int o = idx >> 7, kh = idx & 127;
      const float v = (o < 20) ? w2r[(long)kh * 20 + o] : 0.f;
      lds_w2[o * 136 + kh] = (short)f2bf(v);
    }
  }
  __syncthreads();
  // layer-2: wave w -> m rows [w*16, w*16+16), o 0..31, K=128 (4 steps)
  f32x4 acc2[2];
  acc2[0] = f32x4{0.f, 0.f, 0.f, 0.f};
  acc2[1] = f32x4{0.f, 0.f, 0.f, 0.f};
#pragma unroll
  for (int ks2 = 0; ks2 < 4; ks2++) {
    bf16x8 a0 = *(const bf16x8*)&lds_h[(w * 16 + lm) * 136 + ks2 * 32 + lg * 8];
    bf16x8 b0 = *(const bf16x8*)&lds_w2[lm * 136 + ks2 * 32 + lg * 8];
    bf16x8 b1v = *(const bf16x8*)&lds_w2[(16 + lm) * 136 + ks2 * 32 + lg * 8];
    acc2[0] = mfma16(a0, b0, acc2[0]);
    acc2[1] = mfma16(a0, b1v, acc2[1]);
  }
#pragma unroll
  for (int ni = 0; ni < 2; ni++)
#pragma unroll
    for (int i = 0; i < 4; i++) {
      const int m = w * 16 + lg * 4 + i;
      const int o = ni * 16 + lm;
      if (o < 20)
        atomicAdd(&m1[m * 20 + o], acc2[ni][i] * (1.f / 64.f));
    }
}

// ---------------------------------------------------------------------------
// gemm_n64: out[:, c*64 : c*64+64] = act(X[128,K] @ W[K,N] + bias)
// M=128 x N=64 tiles, BK=64, grid = N/64.
// ---------------------------------------------------------------------------
template<int RELU>
__global__ __launch_bounds__(256)
void gemm_n64(const float* __restrict__ X, int ldx,
              const float* __restrict__ W, int ldw,
              const float* __restrict__ bias,
              float* __restrict__ out, int ldo, int kSteps)
{
  __shared__ short lds_a[128 * 72];
  __shared__ short lds_b[64 * 72];
  __shared__ float biasS[64];

  const int c = blockIdx.x;
  const int t = threadIdx.x;
  const int lane = t & 63;
  const int w = t >> 6;

  if (t < 64) biasS[t] = bias[c * 64 + t];

  const int aRow = t >> 2;
  const int aCol = (t & 3) * 4;
  const int bn   = t & 63;
  const int bk0  = w * 8;

  f32x4 aR[2][4];
  float bR[2][8];

  auto loadTile = [&](int ks) {
    const float* xp = X + (long)aRow * ldx + ks * 64 + aCol;
#pragma unroll
    for (int j = 0; j < 4; j++) {
      aR[0][j] = *(const f32x4*)(xp + 16 * j);
      aR[1][j] = *(const f32x4*)(xp + (long)64 * ldx + 16 * j);
    }
    const float* wp = W + (long)(ks * 64 + bk0) * ldw + c * 64 + bn;
#pragma unroll
    for (int g = 0; g < 2; g++)
#pragma unroll
      for (int j = 0; j < 8; j++)
        bR[g][j] = wp[(long)(g * 32 + j) * ldw];
  };

  auto storeTile = [&]() {
#pragma unroll
    for (int g = 0; g < 2; g++)
#pragma unroll
      for (int j = 0; j < 4; j++) {
        u32x2 v;
        v[0] = pk2(aR[g][j][0], aR[g][j][1]);
        v[1] = pk2(aR[g][j][2], aR[g][j][3]);
        *(u32x2*)&lds_a[(aRow + 64 * g) * 72 + aCol + 16 * j] = v;
      }
#pragma unroll
    for (int g = 0; g < 2; g++) {
      u32x4 v;
      v[0] = pk2(bR[g][0], bR[g][1]);
      v[1] = pk2(bR[g][2], bR[g][3]);
      v[2] = pk2(bR[g][4], bR[g][5]);
      v[3] = pk2(bR[g][6], bR[g][7]);
      *(u32x4*)&lds_b[bn * 72 + bk0 + g * 32] = v;
    }
  };

  const int wm = w & 1, wn = w >> 1;
  const int mBase = wm * 64, nBase = wn * 32;
  const int lm = lane & 15, lg = lane >> 4;

  f32x4 acc[4][2];
#pragma unroll
  for (int i = 0; i < 4; i++)
#pragma unroll
    for (int j = 0; j < 2; j++) acc[i][j] = f32x4{0.f, 0.f, 0.f, 0.f};

  loadTile(0);
  for (int ks = 0; ks < kSteps; ks++) {
    __syncthreads();
    storeTile();
    __syncthreads();
    if (ks + 1 < kSteps) loadTile(ks + 1);
    bf16x8 af[2][4], bfr[2][2];
#pragma unroll
    for (int g = 0; g < 2; g++) {
#pragma unroll
      for (int i = 0; i < 4; i++)
        af[g][i] = *(const bf16x8*)&lds_a[(mBase + i * 16 + lm) * 72 + g * 32 + lg * 8];
#pragma unroll
      for (int j = 0; j < 2; j++)
        bfr[g][j] = *(const bf16x8*)&lds_b[(nBase + j * 16 + lm) * 72 + g * 32 + lg * 8];
    }
#pragma unroll
    for (int mi = 0; mi < 4; mi++)
#pragma unroll
      for (int ni = 0; ni < 2; ni++) {
        acc[mi][ni] = mfma16(af[0][mi], bfr[0][ni], acc[mi][ni]);
        acc[mi][ni] = mfma16(af[1][mi], bfr[1][ni], acc[mi][ni]);
      }
  }

  float* outp = out + c * 64;
#pragma unroll
  for (int mi = 0; mi < 4; mi++)
#pragma unroll
    for (int ni = 0; ni < 2; ni++) {
      const int col = nBase + ni * 16 + lm;
      const float bv = biasS[col];
#pragma unroll
      for (int i = 0; i < 4; i++) {
        const int row = mBase + mi * 16 + lg * 4 + i;
        float v = acc[mi][ni][i] + bv;
        if (RELU) v = v > 0.f ? v : 0.f;
        outp[(long)row * ldo + col] = v;
      }
    }
}

// m1 init: mean over r of b2; k_mlp atomically adds the rest.
__global__ void k_init_m1(const float* __restrict__ b2, float* __restrict__ m1) {
  const int i = blockIdx.x * blockDim.x + threadIdx.x;
  if (i >= 128 * 20) return;
  const int o = i % 20;
  float s = 0.f;
  for (int r = 0; r < 64; r++) s += b2[r * 20 + o];
  m1[i] = s * (1.f / 64.f);
}

// small FC, K fully unrolled (all W loads in flight) for latency
template<int K, int RELU>
__global__ void k_fc_small(const float* __restrict__ in, const float* __restrict__ Wt,
                           const float* __restrict__ bias, float* __restrict__ out,
                           int N)
{
  const int i = blockIdx.x * blockDim.x + threadIdx.x;
  const int b = i / N;
  if (b >= 128) return;
  const int j = i - b * N;
  float s = bias[j];
  const float* ip = in + (long)b * K;
#pragma unroll
  for (int k = 0; k < K; k++) s += ip[k] * Wt[k * N + j];
  out[i] = (RELU && s < 0.f) ? 0.f : s;
}

extern "C" void kernel_launch(void* const* d_in, const int* in_sizes, int n_in,
                              void* d_out, int out_size, void* d_ws, size_t ws_size,
                              hipStream_t stream)
{
  const float* x   = (const float*)d_in[0];
  const float* W1  = (const float*)d_in[3];
  const float* b1  = (const float*)d_in[4];
  const float* W2  = (const float*)d_in[5];
  const float* b2  = (const float*)d_in[6];
  const float* Wg1 = (const float*)d_in[7];
  const float* bg1 = (const float*)d_in[8];
  const float* Wg2 = (const float*)d_in[9];
  const float* bg2 = (const float*)d_in[10];
  const float* Wf1 = (const float*)d_in[11];
  const float* bf1 = (const float*)d_in[12];
  const float* Wf2 = (const float*)d_in[13];
  const float* bf2 = (const float*)d_in[14];
  const float* Wo  = (const float*)d_in[15];
  const float* bo  = (const float*)d_in[16];
  float* out = (float*)d_out;

  float* ws = (float*)d_ws;
  float* m1 = ws;            // 2560 floats
  float* g1 = ws + 4096;     // 8192
  float* g2 = ws + 16384;    // 16384
  float* y1 = ws + 32768;    // 65536
  float* y2 = ws + 98304;    // 131072

  k_init_m1<<<10, 256, 0, stream>>>(b2, m1);
  // dominant: per-ROI 2-layer MLP, 64 ROIs x 4 HID-slices of 128
  k_mlp<<<256, 512, 0, stream>>>(x, W1, b1, W2, m1);
  // collapsed-GCN + FC chain
  k_fc_small<20, 1><<<32, 256, 0, stream>>>(m1, Wg1, bg1, g1, 64);
  k_fc_small<64, 1><<<64, 256, 0, stream>>>(g1, Wg2, bg2, g2, 128);
  gemm_n64<1><<<8,   256, 0, stream>>>(g2, 128,  Wf1, 512,  bf1, y1, 512, 2);
  gemm_n64<1><<<16,  256, 0, stream>>>(y1, 512,  Wf2, 1024, bf2, y2, 1024, 8);
  gemm_n64<0><<<100, 256, 0, stream>>>(y2, 1024, Wo,  6400, bo,  out, 6400, 16);
}

// Round 6
// 501.037 us; speedup vs baseline: 1.1782x; 1.1782x over previous
//
#include <hip/hip_runtime.h>
#include <hip/hip_bf16.h>
#include <cstdint>

typedef float  f32x4 __attribute__((ext_vector_type(4)));
typedef short  s16x4 __attribute__((ext_vector_type(4)));
typedef short  s16x8 __attribute__((ext_vector_type(8)));
typedef __bf16 bf16x8 __attribute__((ext_vector_type(8)));
typedef unsigned int u32x2 __attribute__((ext_vector_type(2)));
typedef unsigned int u32x4 __attribute__((ext_vector_type(4)));

static __device__ __forceinline__ unsigned short f2bf(float f) {
  union { float f; unsigned u; } v; v.f = f;
  unsigned r = v.u + 0x7fffu + ((v.u >> 16) & 1u);   // RTNE
  return (unsigned short)(r >> 16);
}

// packed fp32 pair -> 2x bf16 in one VALU op (RTNE), lo -> bits[15:0]
static __device__ __forceinline__ unsigned pk2(float lo, float hi) {
  unsigned r;
  asm("v_cvt_pk_bf16_f32 %0, %1, %2" : "=v"(r) : "v"(lo), "v"(hi));
  return r;
}

static __device__ __forceinline__ f32x4 mfma16(bf16x8 a, bf16x8 b, f32x4 c) {
  return __builtin_amdgcn_mfma_f32_16x16x32_bf16(a, b, c, 0, 0, 0);
}

// ---------------------------------------------------------------------------
// k_mlp: fused per-ROI 2-layer MLP.
// Round-6: R3's verified structure (M=128 x N=128, grid 256 = 64 r x 4 c,
// depth-1 register staging with STATIC indices — R5's runtime-indexed
// prefetch spilled to scratch, VGPR=68 + 224 µs) with the LDS halved via a
// union: {lds_a, lds_b} (K-loop) and {lds_h, lds_w2} (epilogue) share one
// 43.5 KB buffer, since their live ranges are disjoint (barrier added at
// the handoff). 80.9 -> ~44 KB => 2 blocks/CU; __launch_bounds__(512,4)
// caps VGPR at 128 so 16 waves/CU actually fit. The co-resident block
// hides the per-K-step barrier drain (the overlap 1-block/CU lost).
// K=2048 in 32 steps of BK=64. Epilogue: h = relu(C+b1) -> lds_h,
// P = h @ W2slice -> atomicAdd(m1, P/64).
// ---------------------------------------------------------------------------
__global__ __launch_bounds__(512, 4)
void k_mlp(const float* __restrict__ X, const float* __restrict__ W1,
           const float* __restrict__ b1, const float* __restrict__ W2,
           float* __restrict__ m1)
{
  // union: K-loop {a: 9216, b: 9216} shorts | epilogue {h: 17408, w2: 4352}
  __shared__ short smem[21760];        // 43520 B
  __shared__ float biasS[128];
  short* const lds_a  = smem;          // [m][k] bf16, k padded 64->72
  short* const lds_b  = smem + 9216;   // [n][k] bf16
  short* const lds_h  = smem;          // layer2 A: [m][kh] bf16, kh->136
  short* const lds_w2 = smem + 17408;  // layer2 B: [o][kh] bf16 (o>=20 zero)

  const int bid = blockIdx.x;
  // XCD swizzle: the 4 c-slices of one r land on the same XCD (bid mod 8)
  const int r = (bid & 7) + ((bid >> 5) << 3);
  const int c = (bid >> 3) & 3;

  const float* xr = X + (long)r * (128 * 2048);
  const float* wr = W1 + (long)r * (2048 * 512) + c * 128;
  const float* bp = b1 + (long)r * 512 + c * 128;

  const int t = threadIdx.x;
  const int lane = t & 63;
  const int w = t >> 6;                // 0..7

  if (t < 128) biasS[t] = bp[t];

  // staging maps (BK=64)
  const int aRow = t >> 2;             // 0..127
  const int aCol = (t & 3) * 4;        // within-row float offset, +16j
  const int bn   = t & 127;            // 0..127
  const int bk0  = (t >> 7) * 8;       // k-chunk base: 0 or 8 (+32 for g=1)

  f32x4 aR[4];
  float bR[2][8];

  auto loadTile = [&](int ks) {
    const float* xp = xr + (long)aRow * 2048 + ks * 64 + aCol;
#pragma unroll
    for (int j = 0; j < 4; j++)
      aR[j] = *(const f32x4*)(xp + 16 * j);
    const float* wp = wr + (long)(ks * 64 + bk0) * 512 + bn;
#pragma unroll
    for (int g = 0; g < 2; g++)
#pragma unroll
      for (int j = 0; j < 8; j++)
        bR[g][j] = wp[(long)(g * 32 + j) * 512];
  };

  auto storeTile = [&]() {
#pragma unroll
    for (int j = 0; j < 4; j++) {
      u32x2 v;
      v[0] = pk2(aR[j][0], aR[j][1]);
      v[1] = pk2(aR[j][2], aR[j][3]);
      *(u32x2*)&lds_a[aRow * 72 + aCol + 16 * j] = v;
    }
#pragma unroll
    for (int g = 0; g < 2; g++) {
      u32x4 v;
      v[0] = pk2(bR[g][0], bR[g][1]);
      v[1] = pk2(bR[g][2], bR[g][3]);
      v[2] = pk2(bR[g][4], bR[g][5]);
      v[3] = pk2(bR[g][6], bR[g][7]);
      *(u32x4*)&lds_b[bn * 72 + bk0 + g * 32] = v;
    }
  };

  // 8 waves as 2(m) x 4(n): each wave 64m x 32n; per step 4x2x2 MFMAs
  const int wm = w & 1, wn = w >> 1;
  const int mBase = wm * 64, nBase = wn * 32;
  const int lm = lane & 15, lg = lane >> 4;

  f32x4 acc[4][2];
#pragma unroll
  for (int i = 0; i < 4; i++)
#pragma unroll
    for (int j = 0; j < 2; j++) acc[i][j] = f32x4{0.f, 0.f, 0.f, 0.f};

  loadTile(0);
  for (int ks = 0; ks < 32; ks++) {
    __syncthreads();
    storeTile();
    __syncthreads();
    if (ks + 1 < 32) loadTile(ks + 1);
    bf16x8 af[2][4], bfr[2][2];
#pragma unroll
    for (int g = 0; g < 2; g++) {
#pragma unroll
      for (int i = 0; i < 4; i++)
        af[g][i] = *(const bf16x8*)&lds_a[(mBase + i * 16 + lm) * 72 + g * 32 + lg * 8];
#pragma unroll
      for (int j = 0; j < 2; j++)
        bfr[g][j] = *(const bf16x8*)&lds_b[(nBase + j * 16 + lm) * 72 + g * 32 + lg * 8];
    }
#pragma unroll
    for (int mi = 0; mi < 4; mi++)
#pragma unroll
      for (int ni = 0; ni < 2; ni++) {
        acc[mi][ni] = mfma16(af[0][mi], bfr[0][ni], acc[mi][ni]);
        acc[mi][ni] = mfma16(af[1][mi], bfr[1][ni], acc[mi][ni]);
      }
  }

  // handoff barrier: {a,b} region becomes {h,w2} — all waves must finish
  // their last compute reads before anyone overwrites the union.
  __syncthreads();

  // h = relu(acc + b1) -> lds_h (bf16, A-layout [m][kh], kh = HID-slice col)
#pragma unroll
  for (int mi = 0; mi < 4; mi++)
#pragma unroll
    for (int ni = 0; ni < 2; ni++) {
      const int col = nBase + ni * 16 + lm;      // 0..127
      const float bv = biasS[col];
#pragma unroll
      for (int i = 0; i < 4; i++) {
        const int row = mBase + mi * 16 + lg * 4 + i;
        float v = acc[mi][ni][i] + bv;
        v = v > 0.f ? v : 0.f;
        lds_h[row * 136 + col] = (short)f2bf(v);
      }
    }
  // stage W2 slice [kh 0..127][o 0..19] -> lds_w2[o][kh], zero-pad o>=20
  {
    const float* w2r = W2 + (long)r * (512 * 20) + (long)(c * 128) * 20;
#pragma unroll
    for (int i = 0; i < 8; i++) {
      const int idx = t * 8 + i;            // 0..4095
      const int o = idx >> 7, kh = idx & 127;
      const float v = (o < 20) ? w2r[(long)kh * 20 + o] : 0.f;
      lds_w2[o * 136 + kh] = (short)f2bf(v);
    }
  }
  __syncthreads();
  // layer-2: wave w -> m rows [w*16, w*16+16), o 0..31, K=128 (4 steps)
  f32x4 acc2[2];
  acc2[0] = f32x4{0.f, 0.f, 0.f, 0.f};
  acc2[1] = f32x4{0.f, 0.f, 0.f, 0.f};
#pragma unroll
  for (int ks2 = 0; ks2 < 4; ks2++) {
    bf16x8 a0 = *(const bf16x8*)&lds_h[(w * 16 + lm) * 136 + ks2 * 32 + lg * 8];
    bf16x8 b0 = *(const bf16x8*)&lds_w2[lm * 136 + ks2 * 32 + lg * 8];
    bf16x8 b1v = *(const bf16x8*)&lds_w2[(16 + lm) * 136 + ks2 * 32 + lg * 8];
    acc2[0] = mfma16(a0, b0, acc2[0]);
    acc2[1] = mfma16(a0, b1v, acc2[1]);
  }
#pragma unroll
  for (int ni = 0; ni < 2; ni++)
#pragma unroll
    for (int i = 0; i < 4; i++) {
      const int m = w * 16 + lg * 4 + i;
      const int o = ni * 16 + lm;
      if (o < 20)
        atomicAdd(&m1[m * 20 + o], acc2[ni][i] * (1.f / 64.f));
    }
}

// ---------------------------------------------------------------------------
// gemm_n64: out[:, c*64 : c*64+64] = act(X[128,K] @ W[K,N] + bias)
// M=128 x N=64 tiles, BK=64, grid = N/64.
// ---------------------------------------------------------------------------
template<int RELU>
__global__ __launch_bounds__(256)
void gemm_n64(const float* __restrict__ X, int ldx,
              const float* __restrict__ W, int ldw,
              const float* __restrict__ bias,
              float* __restrict__ out, int ldo, int kSteps)
{
  __shared__ short lds_a[128 * 72];
  __shared__ short lds_b[64 * 72];
  __shared__ float biasS[64];

  const int c = blockIdx.x;
  const int t = threadIdx.x;
  const int lane = t & 63;
  const int w = t >> 6;

  if (t < 64) biasS[t] = bias[c * 64 + t];

  const int aRow = t >> 2;
  const int aCol = (t & 3) * 4;
  const int bn   = t & 63;
  const int bk0  = w * 8;

  f32x4 aR[2][4];
  float bR[2][8];

  auto loadTile = [&](int ks) {
    const float* xp = X + (long)aRow * ldx + ks * 64 + aCol;
#pragma unroll
    for (int j = 0; j < 4; j++) {
      aR[0][j] = *(const f32x4*)(xp + 16 * j);
      aR[1][j] = *(const f32x4*)(xp + (long)64 * ldx + 16 * j);
    }
    const float* wp = W + (long)(ks * 64 + bk0) * ldw + c * 64 + bn;
#pragma unroll
    for (int g = 0; g < 2; g++)
#pragma unroll
      for (int j = 0; j < 8; j++)
        bR[g][j] = wp[(long)(g * 32 + j) * ldw];
  };

  auto storeTile = [&]() {
#pragma unroll
    for (int g = 0; g < 2; g++)
#pragma unroll
      for (int j = 0; j < 4; j++) {
        u32x2 v;
        v[0] = pk2(aR[g][j][0], aR[g][j][1]);
        v[1] = pk2(aR[g][j][2], aR[g][j][3]);
        *(u32x2*)&lds_a[(aRow + 64 * g) * 72 + aCol + 16 * j] = v;
      }
#pragma unroll
    for (int g = 0; g < 2; g++) {
      u32x4 v;
      v[0] = pk2(bR[g][0], bR[g][1]);
      v[1] = pk2(bR[g][2], bR[g][3]);
      v[2] = pk2(bR[g][4], bR[g][5]);
      v[3] = pk2(bR[g][6], bR[g][7]);
      *(u32x4*)&lds_b[bn * 72 + bk0 + g * 32] = v;
    }
  };

  const int wm = w & 1, wn = w >> 1;
  const int mBase = wm * 64, nBase = wn * 32;
  const int lm = lane & 15, lg = lane >> 4;

  f32x4 acc[4][2];
#pragma unroll
  for (int i = 0; i < 4; i++)
#pragma unroll
    for (int j = 0; j < 2; j++) acc[i][j] = f32x4{0.f, 0.f, 0.f, 0.f};

  loadTile(0);
  for (int ks = 0; ks < kSteps; ks++) {
    __syncthreads();
    storeTile();
    __syncthreads();
    if (ks + 1 < kSteps) loadTile(ks + 1);
    bf16x8 af[2][4], bfr[2][2];
#pragma unroll
    for (int g = 0; g < 2; g++) {
#pragma unroll
      for (int i = 0; i < 4; i++)
        af[g][i] = *(const bf16x8*)&lds_a[(mBase + i * 16 + lm) * 72 + g * 32 + lg * 8];
#pragma unroll
      for (int j = 0; j < 2; j++)
        bfr[g][j] = *(const bf16x8*)&lds_b[(nBase + j * 16 + lm) * 72 + g * 32 + lg * 8];
    }
#pragma unroll
    for (int mi = 0; mi < 4; mi++)
#pragma unroll
      for (int ni = 0; ni < 2; ni++) {
        acc[mi][ni] = mfma16(af[0][mi], bfr[0][ni], acc[mi][ni]);
        acc[mi][ni] = mfma16(af[1][mi], bfr[1][ni], acc[mi][ni]);
      }
  }

  float* outp = out + c * 64;
#pragma unroll
  for (int mi = 0; mi < 4; mi++)
#pragma unroll
    for (int ni = 0; ni < 2; ni++) {
      const int col = nBase + ni * 16 + lm;
      const float bv = biasS[col];
#pragma unroll
      for (int i = 0; i < 4; i++) {
        const int row = mBase + mi * 16 + lg * 4 + i;
        float v = acc[mi][ni][i] + bv;
        if (RELU) v = v > 0.f ? v : 0.f;
        outp[(long)row * ldo + col] = v;
      }
    }
}

// m1 init: mean over r of b2; k_mlp atomically adds the rest.
__global__ void k_init_m1(const float* __restrict__ b2, float* __restrict__ m1) {
  const int i = blockIdx.x * blockDim.x + threadIdx.x;
  if (i >= 128 * 20) return;
  const int o = i % 20;
  float s = 0.f;
  for (int r = 0; r < 64; r++) s += b2[r * 20 + o];
  m1[i] = s * (1.f / 64.f);
}

// small FC, K fully unrolled (all W loads in flight) for latency
template<int K, int RELU>
__global__ void k_fc_small(const float* __restrict__ in, const float* __restrict__ Wt,
                           const float* __restrict__ bias, float* __restrict__ out,
                           int N)
{
  const int i = blockIdx.x * blockDim.x + threadIdx.x;
  const int b = i / N;
  if (b >= 128) return;
  const int j = i - b * N;
  float s = bias[j];
  const float* ip = in + (long)b * K;
#pragma unroll
  for (int k = 0; k < K; k++) s += ip[k] * Wt[k * N + j];
  out[i] = (RELU && s < 0.f) ? 0.f : s;
}

extern "C" void kernel_launch(void* const* d_in, const int* in_sizes, int n_in,
                              void* d_out, int out_size, void* d_ws, size_t ws_size,
                              hipStream_t stream)
{
  const float* x   = (const float*)d_in[0];
  const float* W1  = (const float*)d_in[3];
  const float* b1  = (const float*)d_in[4];
  const float* W2  = (const float*)d_in[5];
  const float* b2  = (const float*)d_in[6];
  const float* Wg1 = (const float*)d_in[7];
  const float* bg1 = (const float*)d_in[8];
  const float* Wg2 = (const float*)d_in[9];
  const float* bg2 = (const float*)d_in[10];
  const float* Wf1 = (const float*)d_in[11];
  const float* bf1 = (const float*)d_in[12];
  const float* Wf2 = (const float*)d_in[13];
  const float* bf2 = (const float*)d_in[14];
  const float* Wo  = (const float*)d_in[15];
  const float* bo  = (const float*)d_in[16];
  float* out = (float*)d_out;

  float* ws = (float*)d_ws;
  float* m1 = ws;            // 2560 floats
  float* g1 = ws + 4096;     // 8192
  float* g2 = ws + 16384;    // 16384
  float* y1 = ws + 32768;    // 65536
  float* y2 = ws + 98304;    // 131072

  k_init_m1<<<10, 256, 0, stream>>>(b2, m1);
  // dominant: per-ROI 2-layer MLP, 64 ROIs x 4 HID-slices of 128
  k_mlp<<<256, 512, 0, stream>>>(x, W1, b1, W2, m1);
  // collapsed-GCN + FC chain
  k_fc_small<20, 1><<<32, 256, 0, stream>>>(m1, Wg1, bg1, g1, 64);
  k_fc_small<64, 1><<<64, 256, 0, stream>>>(g1, Wg2, bg2, g2, 128);
  gemm_n64<1><<<8,   256, 0, stream>>>(g2, 128,  Wf1, 512,  bf1, y1, 512, 2);
  gemm_n64<1><<<16,  256, 0, stream>>>(y1, 512,  Wf2, 1024, bf2, y2, 1024, 8);
  gemm_n64<0><<<100, 256, 0, stream>>>(y2, 1024, Wo,  6400, bo,  out, 6400, 16);
}

// Round 7
// 495.607 us; speedup vs baseline: 1.1911x; 1.0110x over previous
//
#include <hip/hip_runtime.h>
#include <hip/hip_bf16.h>
#include <cstdint>

typedef float  f32x4 __attribute__((ext_vector_type(4)));
typedef short  s16x4 __attribute__((ext_vector_type(4)));
typedef short  s16x8 __attribute__((ext_vector_type(8)));
typedef __bf16 bf16x8 __attribute__((ext_vector_type(8)));
typedef unsigned int u32x2 __attribute__((ext_vector_type(2)));
typedef unsigned int u32x4 __attribute__((ext_vector_type(4)));

static __device__ __forceinline__ unsigned short f2bf(float f) {
  union { float f; unsigned u; } v; v.f = f;
  unsigned r = v.u + 0x7fffu + ((v.u >> 16) & 1u);   // RTNE
  return (unsigned short)(r >> 16);
}

// packed fp32 pair -> 2x bf16 in one VALU op (RTNE), lo -> bits[15:0]
static __device__ __forceinline__ unsigned pk2(float lo, float hi) {
  unsigned r;
  asm("v_cvt_pk_bf16_f32 %0, %1, %2" : "=v"(r) : "v"(lo), "v"(hi));
  return r;
}

static __device__ __forceinline__ f32x4 mfma16(bf16x8 a, bf16x8 b, f32x4 c) {
  return __builtin_amdgcn_mfma_f32_16x16x32_bf16(a, b, c, 0, 0, 0);
}

// ---------------------------------------------------------------------------
// k_mlp: fused per-ROI 2-layer MLP.
// Round-7: depth-2 register prefetch done RIGHT. R5's version spilled to
// scratch (runtime-indexed ext_vector arrays, rule #20: VGPR=68 + 224 µs).
// Here: two NAMED staging sets (aR0/bR0, aR1/bR1), K-loop manually unrolled
// x2, every index compile-time static. Load->use distance = 2 full K-steps
// (~2.5K+ cyc) > HBM latency (~900 cyc), so storeTile's vmcnt wait no longer
// exposes memory latency every step — the diagnosed ~3K-cyc/step stall
// (k_mlp = 135 µs = 10K cyc/step vs ~1.5K of real work, 1 block/CU barrier-
// locked). No __launch_bounds__ VGPR cap: prefetch state needs ~150 VGPR.
// Geometry unchanged from verified R6: M=128 x N=128, grid 256 = 64 r x 4 c,
// XCD-swizzled; LDS union {a,b}|{h,w2} 43.5 KB; epilogue verified 3x.
// ---------------------------------------------------------------------------
__global__ __launch_bounds__(512)
void k_mlp(const float* __restrict__ X, const float* __restrict__ W1,
           const float* __restrict__ b1, const float* __restrict__ W2,
           float* __restrict__ m1)
{
  // union: K-loop {a: 9216, b: 9216} shorts | epilogue {h: 17408, w2: 4352}
  __shared__ short smem[21760];        // 43520 B
  __shared__ float biasS[128];
  short* const lds_a  = smem;          // [m][k] bf16, k padded 64->72
  short* const lds_b  = smem + 9216;   // [n][k] bf16
  short* const lds_h  = smem;          // layer2 A: [m][kh] bf16, kh->136
  short* const lds_w2 = smem + 17408;  // layer2 B: [o][kh] bf16 (o>=20 zero)

  const int bid = blockIdx.x;
  // XCD swizzle: the 4 c-slices of one r land on the same XCD (bid mod 8)
  const int r = (bid & 7) + ((bid >> 5) << 3);
  const int c = (bid >> 3) & 3;

  const float* xr = X + (long)r * (128 * 2048);
  const float* wr = W1 + (long)r * (2048 * 512) + c * 128;
  const float* bp = b1 + (long)r * 512 + c * 128;

  const int t = threadIdx.x;
  const int lane = t & 63;
  const int w = t >> 6;                // 0..7

  if (t < 128) biasS[t] = bp[t];

  // staging maps (BK=64)
  const int aRow = t >> 2;             // 0..127
  const int aCol = (t & 3) * 4;        // within-row float offset, +16j
  const int bn   = t & 127;            // 0..127
  const int bk0  = (t >> 7) * 8;       // k-chunk base: 0,8,16,24 (+32 for g=1)

  // TWO named staging sets — depth-2 prefetch, all indices static (rule #20)
  f32x4 aR0[4], aR1[4];
  float bR0[2][8], bR1[2][8];

  auto loadTile = [&](int ks, f32x4 (&aS)[4], float (&bS)[2][8]) {
    const float* xp = xr + (long)aRow * 2048 + ks * 64 + aCol;
#pragma unroll
    for (int j = 0; j < 4; j++)
      aS[j] = *(const f32x4*)(xp + 16 * j);
    const float* wp = wr + (long)(ks * 64 + bk0) * 512 + bn;
#pragma unroll
    for (int g = 0; g < 2; g++)
#pragma unroll
      for (int j = 0; j < 8; j++)
        bS[g][j] = wp[(long)(g * 32 + j) * 512];
  };

  auto storeTile = [&](f32x4 (&aS)[4], float (&bS)[2][8]) {
#pragma unroll
    for (int j = 0; j < 4; j++) {
      u32x2 v;
      v[0] = pk2(aS[j][0], aS[j][1]);
      v[1] = pk2(aS[j][2], aS[j][3]);
      *(u32x2*)&lds_a[aRow * 72 + aCol + 16 * j] = v;
    }
#pragma unroll
    for (int g = 0; g < 2; g++) {
      u32x4 v;
      v[0] = pk2(bS[g][0], bS[g][1]);
      v[1] = pk2(bS[g][2], bS[g][3]);
      v[2] = pk2(bS[g][4], bS[g][5]);
      v[3] = pk2(bS[g][6], bS[g][7]);
      *(u32x4*)&lds_b[bn * 72 + bk0 + g * 32] = v;
    }
  };

  // 8 waves as 2(m) x 4(n): each wave 64m x 32n; per step 4x2x2 MFMAs
  const int wm = w & 1, wn = w >> 1;
  const int mBase = wm * 64, nBase = wn * 32;
  const int lm = lane & 15, lg = lane >> 4;

  f32x4 acc[4][2];
#pragma unroll
  for (int i = 0; i < 4; i++)
#pragma unroll
    for (int j = 0; j < 2; j++) acc[i][j] = f32x4{0.f, 0.f, 0.f, 0.f};

  auto compute = [&]() {
    bf16x8 af[2][4], bfr[2][2];
#pragma unroll
    for (int g = 0; g < 2; g++) {
#pragma unroll
      for (int i = 0; i < 4; i++)
        af[g][i] = *(const bf16x8*)&lds_a[(mBase + i * 16 + lm) * 72 + g * 32 + lg * 8];
#pragma unroll
      for (int j = 0; j < 2; j++)
        bfr[g][j] = *(const bf16x8*)&lds_b[(nBase + j * 16 + lm) * 72 + g * 32 + lg * 8];
    }
#pragma unroll
    for (int mi = 0; mi < 4; mi++)
#pragma unroll
      for (int ni = 0; ni < 2; ni++) {
        acc[mi][ni] = mfma16(af[0][mi], bfr[0][ni], acc[mi][ni]);
        acc[mi][ni] = mfma16(af[1][mi], bfr[1][ni], acc[mi][ni]);
      }
  };

  loadTile(0, aR0, bR0);
  loadTile(1, aR1, bR1);
  for (int ks = 0; ks < 32; ks += 2) {
    // even step: consumes set0 (tile ks), refills set0 with tile ks+2
    __syncthreads();
    storeTile(aR0, bR0);
    __syncthreads();
    if (ks + 2 < 32) loadTile(ks + 2, aR0, bR0);
    compute();
    // odd step: consumes set1 (tile ks+1), refills set1 with tile ks+3
    __syncthreads();
    storeTile(aR1, bR1);
    __syncthreads();
    if (ks + 3 < 32) loadTile(ks + 3, aR1, bR1);
    compute();
  }

  // handoff barrier: {a,b} region becomes {h,w2} — all waves must finish
  // their last compute reads before anyone overwrites the union.
  __syncthreads();

  // h = relu(acc + b1) -> lds_h (bf16, A-layout [m][kh], kh = HID-slice col)
#pragma unroll
  for (int mi = 0; mi < 4; mi++)
#pragma unroll
    for (int ni = 0; ni < 2; ni++) {
      const int col = nBase + ni * 16 + lm;      // 0..127
      const float bv = biasS[col];
#pragma unroll
      for (int i = 0; i < 4; i++) {
        const int row = mBase + mi * 16 + lg * 4 + i;
        float v = acc[mi][ni][i] + bv;
        v = v > 0.f ? v : 0.f;
        lds_h[row * 136 + col] = (short)f2bf(v);
      }
    }
  // stage W2 slice [kh 0..127][o 0..19] -> lds_w2[o][kh], zero-pad o>=20
  {
    const float* w2r = W2 + (long)r * (512 * 20) + (long)(c * 128) * 20;
#pragma unroll
    for (int i = 0; i < 8; i++) {
      const int idx = t * 8 + i;            // 0..4095
      const int o = idx >> 7, kh = idx & 127;
      const float v = (o < 20) ? w2r[(long)kh * 20 + o] : 0.f;
      lds_w2[o * 136 + kh] = (short)f2bf(v);
    }
  }
  __syncthreads();
  // layer-2: wave w -> m rows [w*16, w*16+16), o 0..31, K=128 (4 steps)
  f32x4 acc2[2];
  acc2[0] = f32x4{0.f, 0.f, 0.f, 0.f};
  acc2[1] = f32x4{0.f, 0.f, 0.f, 0.f};
#pragma unroll
  for (int ks2 = 0; ks2 < 4; ks2++) {
    bf16x8 a0 = *(const bf16x8*)&lds_h[(w * 16 + lm) * 136 + ks2 * 32 + lg * 8];
    bf16x8 b0 = *(const bf16x8*)&lds_w2[lm * 136 + ks2 * 32 + lg * 8];
    bf16x8 b1v = *(const bf16x8*)&lds_w2[(16 + lm) * 136 + ks2 * 32 + lg * 8];
    acc2[0] = mfma16(a0, b0, acc2[0]);
    acc2[1] = mfma16(a0, b1v, acc2[1]);
  }
#pragma unroll
  for (int ni = 0; ni < 2; ni++)
#pragma unroll
    for (int i = 0; i < 4; i++) {
      const int m = w * 16 + lg * 4 + i;
      const int o = ni * 16 + lm;
      if (o < 20)
        atomicAdd(&m1[m * 20 + o], acc2[ni][i] * (1.f / 64.f));
    }
}

// ---------------------------------------------------------------------------
// gemm_n64: out[:, c*64 : c*64+64] = act(X[128,K] @ W[K,N] + bias)
// M=128 x N=64 tiles, BK=64, grid = N/64.
// ---------------------------------------------------------------------------
template<int RELU>
__global__ __launch_bounds__(256)
void gemm_n64(const float* __restrict__ X, int ldx,
              const float* __restrict__ W, int ldw,
              const float* __restrict__ bias,
              float* __restrict__ out, int ldo, int kSteps)
{
  __shared__ short lds_a[128 * 72];
  __shared__ short lds_b[64 * 72];
  __shared__ float biasS[64];

  const int c = blockIdx.x;
  const int t = threadIdx.x;
  const int lane = t & 63;
  const int w = t >> 6;

  if (t < 64) biasS[t] = bias[c * 64 + t];

  const int aRow = t >> 2;
  const int aCol = (t & 3) * 4;
  const int bn   = t & 63;
  const int bk0  = w * 8;

  f32x4 aR[2][4];
  float bR[2][8];

  auto loadTile = [&](int ks) {
    const float* xp = X + (long)aRow * ldx + ks * 64 + aCol;
#pragma unroll
    for (int j = 0; j < 4; j++) {
      aR[0][j] = *(const f32x4*)(xp + 16 * j);
      aR[1][j] = *(const f32x4*)(xp + (long)64 * ldx + 16 * j);
    }
    const float* wp = W + (long)(ks * 64 + bk0) * ldw + c * 64 + bn;
#pragma unroll
    for (int g = 0; g < 2; g++)
#pragma unroll
      for (int j = 0; j < 8; j++)
        bR[g][j] = wp[(long)(g * 32 + j) * ldw];
  };

  auto storeTile = [&]() {
#pragma unroll
    for (int g = 0; g < 2; g++)
#pragma unroll
      for (int j = 0; j < 4; j++) {
        u32x2 v;
        v[0] = pk2(aR[g][j][0], aR[g][j][1]);
        v[1] = pk2(aR[g][j][2], aR[g][j][3]);
        *(u32x2*)&lds_a[(aRow + 64 * g) * 72 + aCol + 16 * j] = v;
      }
#pragma unroll
    for (int g = 0; g < 2; g++) {
      u32x4 v;
      v[0] = pk2(bR[g][0], bR[g][1]);
      v[1] = pk2(bR[g][2], bR[g][3]);
      v[2] = pk2(bR[g][4], bR[g][5]);
      v[3] = pk2(bR[g][6], bR[g][7]);
      *(u32x4*)&lds_b[bn * 72 + bk0 + g * 32] = v;
    }
  };

  const int wm = w & 1, wn = w >> 1;
  const int mBase = wm * 64, nBase = wn * 32;
  const int lm = lane & 15, lg = lane >> 4;

  f32x4 acc[4][2];
#pragma unroll
  for (int i = 0; i < 4; i++)
#pragma unroll
    for (int j = 0; j < 2; j++) acc[i][j] = f32x4{0.f, 0.f, 0.f, 0.f};

  loadTile(0);
  for (int ks = 0; ks < kSteps; ks++) {
    __syncthreads();
    storeTile();
    __syncthreads();
    if (ks + 1 < kSteps) loadTile(ks + 1);
    bf16x8 af[2][4], bfr[2][2];
#pragma unroll
    for (int g = 0; g < 2; g++) {
#pragma unroll
      for (int i = 0; i < 4; i++)
        af[g][i] = *(const bf16x8*)&lds_a[(mBase + i * 16 + lm) * 72 + g * 32 + lg * 8];
#pragma unroll
      for (int j = 0; j < 2; j++)
        bfr[g][j] = *(const bf16x8*)&lds_b[(nBase + j * 16 + lm) * 72 + g * 32 + lg * 8];
    }
#pragma unroll
    for (int mi = 0; mi < 4; mi++)
#pragma unroll
      for (int ni = 0; ni < 2; ni++) {
        acc[mi][ni] = mfma16(af[0][mi], bfr[0][ni], acc[mi][ni]);
        acc[mi][ni] = mfma16(af[1][mi], bfr[1][ni], acc[mi][ni]);
      }
  }

  float* outp = out + c * 64;
#pragma unroll
  for (int mi = 0; mi < 4; mi++)
#pragma unroll
    for (int ni = 0; ni < 2; ni++) {
      const int col = nBase + ni * 16 + lm;
      const float bv = biasS[col];
#pragma unroll
      for (int i = 0; i < 4; i++) {
        const int row = mBase + mi * 16 + lg * 4 + i;
        float v = acc[mi][ni][i] + bv;
        if (RELU) v = v > 0.f ? v : 0.f;
        outp[(long)row * ldo + col] = v;
      }
    }
}

// m1 init: mean over r of b2; k_mlp atomically adds the rest.
__global__ void k_init_m1(const float* __restrict__ b2, float* __restrict__ m1) {
  const int i = blockIdx.x * blockDim.x + threadIdx.x;
  if (i >= 128 * 20) return;
  const int o = i % 20;
  float s = 0.f;
  for (int r = 0; r < 64; r++) s += b2[r * 20 + o];
  m1[i] = s * (1.f / 64.f);
}

// small FC, K fully unrolled (all W loads in flight) for latency
template<int K, int RELU>
__global__ void k_fc_small(const float* __restrict__ in, const float* __restrict__ Wt,
                           const float* __restrict__ bias, float* __restrict__ out,
                           int N)
{
  const int i = blockIdx.x * blockDim.x + threadIdx.x;
  const int b = i / N;
  if (b >= 128) return;
  const int j = i - b * N;
  float s = bias[j];
  const float* ip = in + (long)b * K;
#pragma unroll
  for (int k = 0; k < K; k++) s += ip[k] * Wt[k * N + j];
  out[i] = (RELU && s < 0.f) ? 0.f : s;
}

extern "C" void kernel_launch(void* const* d_in, const int* in_sizes, int n_in,
                              void* d_out, int out_size, void* d_ws, size_t ws_size,
                              hipStream_t stream)
{
  const float* x   = (const float*)d_in[0];
  const float* W1  = (const float*)d_in[3];
  const float* b1  = (const float*)d_in[4];
  const float* W2  = (const float*)d_in[5];
  const float* b2  = (const float*)d_in[6];
  const float* Wg1 = (const float*)d_in[7];
  const float* bg1 = (const float*)d_in[8];
  const float* Wg2 = (const float*)d_in[9];
  const float* bg2 = (const float*)d_in[10];
  const float* Wf1 = (const float*)d_in[11];
  const float* bf1 = (const float*)d_in[12];
  const float* Wf2 = (const float*)d_in[13];
  const float* bf2 = (const float*)d_in[14];
  const float* Wo  = (const float*)d_in[15];
  const float* bo  = (const float*)d_in[16];
  float* out = (float*)d_out;

  float* ws = (float*)d_ws;
  float* m1 = ws;            // 2560 floats
  float* g1 = ws + 4096;     // 8192
  float* g2 = ws + 16384;    // 16384
  float* y1 = ws + 32768;    // 65536
  float* y2 = ws + 98304;    // 131072

  k_init_m1<<<10, 256, 0, stream>>>(b2, m1);
  // dominant: per-ROI 2-layer MLP, 64 ROIs x 4 HID-slices of 128
  k_mlp<<<256, 512, 0, stream>>>(x, W1, b1, W2, m1);
  // collapsed-GCN + FC chain
  k_fc_small<20, 1><<<32, 256, 0, stream>>>(m1, Wg1, bg1, g1, 64);
  k_fc_small<64, 1><<<64, 256, 0, stream>>>(g1, Wg2, bg2, g2, 128);
  gemm_n64<1><<<8,   256, 0, stream>>>(g2, 128,  Wf1, 512,  bf1, y1, 512, 2);
  gemm_n64<1><<<16,  256, 0, stream>>>(y1, 512,  Wf2, 1024, bf2, y2, 1024, 8);
  gemm_n64<0><<<100, 256, 0, stream>>>(y2, 1024, Wo,  6400, bo,  out, 6400, 16);
}